// Round 6
// baseline (128.287 us; speedup 1.0000x reference)
//
#include <hip/hip_runtime.h>
#include <hip/hip_bf16.h>
#include <math.h>

// Problem constants (from reference): B=2048, I=512, O=512
#define B_DIM 2048
#define I_DIM 512
#define O_DIM 512

// ws layout:
//   abT: [0, 2MB)    abT_f4[o*256 + st*4 + j], st=0..63, j=0..3
//        j-th float4 = (a_{8st+2j}, b_{8st+2j}, a_{8st+2j+1}, b_{8st+2j+1})
//   xt2: [2MB, 6MB)  xt2_f4[iq*2048 + b] = x[b][4iq .. 4iq+3]
//   [6MB, 256MB): slack — dead last-iteration prefetch overruns land here.
#define ABT_OFFSET 0
#define XT2_OFFSET ((size_t)2 * 1024 * 1024)

// ---------------------------------------------------------------------------
// Setup: blocks [0,128) build abT, blocks [128,1152) transpose x.
//   factor[b,i,o] = a[i,o] + bcoef[i,o]*x[b,i];  a = 1-w*s, b = w*(2s-1)
// ---------------------------------------------------------------------------
__global__ __launch_bounds__(256) void setup_kernel(
    const float* __restrict__ x,
    const float* __restrict__ w_logits,
    const float* __restrict__ s_logits,
    float4* __restrict__ abT,
    float4* __restrict__ xt2)
{
    const int blk = blockIdx.x;
    if (blk < 128) {
        int t  = blk * 256 + threadIdx.x;    // 0..32767
        int o  = t & (O_DIM - 1);            // lane-fast -> coalesced w/s reads
        int st = t >> 9;                     // 8-i stage, 0..63
#pragma unroll
        for (int j = 0; j < 4; ++j) {
            int i0 = 8 * st + 2 * j;
            float zw0 = w_logits[(i0 + 0) * O_DIM + o];
            float zs0 = s_logits[(i0 + 0) * O_DIM + o];
            float zw1 = w_logits[(i0 + 1) * O_DIM + o];
            float zs1 = s_logits[(i0 + 1) * O_DIM + o];
            float w0 = 1.0f / (1.0f + expf(-zw0));
            float s0 = 1.0f / (1.0f + expf(-zs0));
            float w1 = 1.0f / (1.0f + expf(-zw1));
            float s1 = 1.0f / (1.0f + expf(-zs1));
            float4 v;
            v.x = fmaf(-w0, s0, 1.0f);        // a0
            v.y = w0 * (2.0f * s0 - 1.0f);    // b0
            v.z = fmaf(-w1, s1, 1.0f);        // a1
            v.w = w1 * (2.0f * s1 - 1.0f);    // b1
            abT[(size_t)o * 256 + st * 4 + j] = v;
        }
    } else {
        int t  = (blk - 128) * 256 + threadIdx.x;  // 0..262143
        int iq = t & 127;                          // lane-fast -> coalesced read
        int b  = t >> 7;
        float4 v = ((const float4*)x)[(size_t)b * 128 + iq];
        xt2[(size_t)iq * B_DIM + b] = v;           // scattered 16B write, 4MB total
    }
}

// ---------------------------------------------------------------------------
// Main: lane = b, wave = one o. Block 512 = 8 waves (8 o's) x 64 b's.
// Grid (B/64, O/8) = (32, 64) = 2048 blocks.
//   x  : lane-varying coalesced global_load_dwordx4 (vmcnt, in-order).
//   ab : wave-uniform broadcast global loads (vmcnt too — NO smem/lgkmcnt
//        drains in the hot loop; R5's s_load ping-pong was structurally
//        defeated by out-of-order SMEM forcing lgkmcnt(0) every stage).
//   8-i stages, depth-2 ping-pong on both streams, 8 independent acc chains.
// ---------------------------------------------------------------------------
__global__ __launch_bounds__(512, 7) void fuzzy_main(
    const float4* __restrict__ abT,
    const float4* __restrict__ xt2,
    float* __restrict__ out)
{
    __shared__ float tile[8 * 65];            // padded: conflict-free epilogue

    const int tid  = threadIdx.x;
    const int lane = tid & 63;
    const int wv   = __builtin_amdgcn_readfirstlane(tid >> 6);  // 0..7
    const int b0   = blockIdx.x * 64;
    const int o    = blockIdx.y * 8 + wv;     // wave-uniform

    const float4* __restrict__ abp  = abT + (size_t)o * 256;    // uniform
    const float4* __restrict__ xcol = xt2 + b0 + lane;          // lane-varying

    // Ping-pong preload: stage A = st, stage B = st+1.
    float4 cA0 = abp[0], cA1 = abp[1], cA2 = abp[2], cA3 = abp[3];
    float4 cB0 = abp[4], cB1 = abp[5], cB2 = abp[6], cB3 = abp[7];
    float4 xA0 = xcol[0],        xA1 = xcol[B_DIM];
    float4 xB0 = xcol[2 * B_DIM], xB1 = xcol[3 * B_DIM];

    float acc0 = 1.0f, acc1 = 1.0f, acc2 = 1.0f, acc3 = 1.0f;
    float acc4 = 1.0f, acc5 = 1.0f, acc6 = 1.0f, acc7 = 1.0f;

    for (int st = 0; st < 64; st += 2) {
        // ---- stage A: i = 8*st .. 8*st+7 ----
        {
            float f0 = fmaf(cA0.y, xA0.x, cA0.x);
            float f1 = fmaf(cA0.w, xA0.y, cA0.z);
            float f2 = fmaf(cA1.y, xA0.z, cA1.x);
            float f3 = fmaf(cA1.w, xA0.w, cA1.z);
            float f4 = fmaf(cA2.y, xA1.x, cA2.x);
            float f5 = fmaf(cA2.w, xA1.y, cA2.z);
            float f6 = fmaf(cA3.y, xA1.z, cA3.x);
            float f7 = fmaf(cA3.w, xA1.w, cA3.z);
            acc0 *= f0; acc1 *= f1; acc2 *= f2; acc3 *= f3;
            acc4 *= f4; acc5 *= f5; acc6 *= f6; acc7 *= f7;
            // Prefetch stage st+2. Last-iter loads (st=64,65) are dead and
            // land in ws slack past xt2/abT — in bounds of the 256MB ws.
            const float4* ap = abp + (size_t)(st + 2) * 4;
            cA0 = ap[0]; cA1 = ap[1]; cA2 = ap[2]; cA3 = ap[3];
            const float4* xp = xcol + (size_t)(2 * (st + 2)) * B_DIM;
            xA0 = xp[0]; xA1 = xp[B_DIM];
        }
        // ---- stage B: i = 8*(st+1) .. 8*(st+1)+7 ----
        {
            float f0 = fmaf(cB0.y, xB0.x, cB0.x);
            float f1 = fmaf(cB0.w, xB0.y, cB0.z);
            float f2 = fmaf(cB1.y, xB0.z, cB1.x);
            float f3 = fmaf(cB1.w, xB0.w, cB1.z);
            float f4 = fmaf(cB2.y, xB1.x, cB2.x);
            float f5 = fmaf(cB2.w, xB1.y, cB2.z);
            float f6 = fmaf(cB3.y, xB1.z, cB3.x);
            float f7 = fmaf(cB3.w, xB1.w, cB3.z);
            acc0 *= f0; acc1 *= f1; acc2 *= f2; acc3 *= f3;
            acc4 *= f4; acc5 *= f5; acc6 *= f6; acc7 *= f7;
            const float4* ap = abp + (size_t)(st + 3) * 4;
            cB0 = ap[0]; cB1 = ap[1]; cB2 = ap[2]; cB3 = ap[3];
            const float4* xp = xcol + (size_t)(2 * (st + 3)) * B_DIM;
            xB0 = xp[0]; xB1 = xp[B_DIM];
        }
    }

    float p = ((acc0 * acc1) * (acc2 * acc3)) * ((acc4 * acc5) * (acc6 * acc7));

    // Epilogue: transpose through LDS so stores are o-fast (32B segments
    // instead of 4B/lane at 2KB stride).
    tile[wv * 65 + lane] = p;
    __syncthreads();
    int o_r = tid & 7;                        // o within tile
    int b_r = tid >> 3;                       // b within tile
    out[(size_t)(b0 + b_r) * O_DIM + blockIdx.y * 8 + o_r] = tile[o_r * 65 + b_r];
}

extern "C" void kernel_launch(void* const* d_in, const int* in_sizes, int n_in,
                              void* d_out, int out_size, void* d_ws, size_t ws_size,
                              hipStream_t stream) {
    const float* x        = (const float*)d_in[0];   // (B, I) fp32
    const float* w_logits = (const float*)d_in[1];   // (I, O) fp32
    const float* s_logits = (const float*)d_in[2];   // (I, O) fp32
    float* out = (float*)d_out;                      // (B, O) fp32
    float4* abT = (float4*)((char*)d_ws + ABT_OFFSET);   // [0, 2MB)
    float4* xt2 = (float4*)((char*)d_ws + XT2_OFFSET);   // [2MB, 6MB)

    // Fused setup: 128 abT-blocks + 1024 x-transpose blocks.
    setup_kernel<<<dim3(1152), dim3(256), 0, stream>>>(
        x, w_logits, s_logits, abT, xt2);

    // Grid (B/64, O/8) = (32, 64) = 2048 blocks of 512 threads.
    fuzzy_main<<<dim3(B_DIM / 64, O_DIM / 8), dim3(512), 0, stream>>>(
        abT, xt2, out);
}